// Round 17
// baseline (445.836 us; speedup 1.0000x reference)
//
#include <hip/hip_runtime.h>
#include <hip/hip_bf16.h>
#include <stdint.h>

#define D 128
#define NSLOT 32

typedef unsigned int u32;
typedef unsigned short u16;
typedef __attribute__((ext_vector_type(8))) short short8;
typedef __attribute__((ext_vector_type(4))) float f32x4;

__device__ __forceinline__ float bf2f(u32 lo16) {
  return __uint_as_float(lo16 << 16);
}
__device__ __forceinline__ u16 f2bf(float f) {
  u32 u = __float_as_uint(f);
  u32 r = (u + 0x7FFFu + ((u >> 16) & 1u)) >> 16;
  return (u16)r;
}
__device__ __forceinline__ u32 pack2(float a, float b) {
  return (u32)f2bf(a) | ((u32)f2bf(b) << 16);
}

// async global->LDS, 16B per lane; lds dest must be wave-uniform base (+lane*16)
__device__ __forceinline__ void gload16(const void* g, void* l) {
  __builtin_amdgcn_global_load_lds(
      (const __attribute__((address_space(1))) u32*)g,
      (__attribute__((address_space(3))) u32*)l, 16, 0, 0);
}

// swizzles (involutions on byte offsets)
#define ASWZ(r, b) ((b) ^ (((r)&7) << 4))                      // 128B rows
#define CSWZ(r, b) ((b) ^ (((r)&7) << 4) ^ (((r)&8) << 1))     // 256B rows

#define BN_EPS 1e-5f

// ---------------- merged front: convert x, convert weights, edge count ----------------
__global__ __launch_bounds__(256)
void k_front(const float* __restrict__ x, u16* __restrict__ B0, int n4x, int nbx,
             const float* __restrict__ Wi, const float* __restrict__ W1,
             const float* __restrict__ W2, u16* __restrict__ oWi,
             u16* __restrict__ oW1, u16* __restrict__ oW2, int na, int nb, int nbw,
             const int* __restrict__ dst, int* __restrict__ cnt, int E) {
  int b = blockIdx.x;
  if (b < nbx) {
    int i = b * 256 + threadIdx.x;
    if (i < n4x) {
      float4 v = ((const float4*)x)[i];
      ushort4 o;
      o.x = f2bf(v.x); o.y = f2bf(v.y); o.z = f2bf(v.z); o.w = f2bf(v.w);
      ((ushort4*)B0)[i] = o;
    }
  } else if (b < nbx + nbw) {
    int i = (b - nbx) * 256 + threadIdx.x;
    const float* in;
    u16* out;
    int idx;
    if (i < na) { in = Wi; out = oWi; idx = i; }
    else if (i < na + nb) { in = W1; out = oW1; idx = i - na; }
    else if (i < na + 2 * nb) { in = W2; out = oW2; idx = i - na - nb; }
    else return;
    float4 v = ((const float4*)in)[idx];
    ushort4 o;
    o.x = f2bf(v.x); o.y = f2bf(v.y); o.z = f2bf(v.z); o.w = f2bf(v.w);
    ((ushort4*)out)[idx] = o;
  } else {
    int e = (b - nbx - nbw) * 256 + threadIdx.x;
    if (e < E) atomicAdd(&cnt[dst[e]], 1);
  }
}

// ---------------- CSR build ----------------
__global__ void k_scan1(const int* __restrict__ cnt, int* __restrict__ rp,
                        int* __restrict__ bsum, int N) {
  __shared__ int sh[256];
  int tid = threadIdx.x;
  int i = blockIdx.x * 256 + tid;
  int v = (i < N) ? cnt[i] : 0;
  sh[tid] = v;
  __syncthreads();
  for (int o = 1; o < 256; o <<= 1) {
    int x = (tid >= o) ? sh[tid - o] : 0;
    __syncthreads();
    sh[tid] += x;
    __syncthreads();
  }
  if (i < N) rp[i] = sh[tid] - v;
  if (tid == 255) bsum[blockIdx.x] = sh[255];
}

__global__ void k_scan2(int* __restrict__ bsum, int NB) {
  __shared__ int sh[512];
  int tid = threadIdx.x;
  int v = (tid < NB) ? bsum[tid] : 0;
  sh[tid] = v;
  __syncthreads();
  for (int o = 1; o < 512; o <<= 1) {
    int x = (tid >= o) ? sh[tid - o] : 0;
    __syncthreads();
    sh[tid] += x;
    __syncthreads();
  }
  if (tid < NB) bsum[tid] = sh[tid] - v;
}

__global__ void k_scan3(int* __restrict__ rp, const int* __restrict__ bsum, int N, int E) {
  int i = blockIdx.x * 256 + threadIdx.x;
  if (i < N) rp[i] += bsum[blockIdx.x];
  if (i == 0) rp[N] = E;
}

__global__ void k_scatter(const int* __restrict__ src, const int* __restrict__ dst,
                          const int* __restrict__ rp, int* __restrict__ fill,
                          int* __restrict__ csr, int E) {
  int e = blockIdx.x * blockDim.x + threadIdx.x;
  if (e < E) {
    int d2 = dst[e];
    int pos = rp[d2] + atomicAdd(&fill[d2], 1);
    csr[pos] = src[e];
  }
}

// ---------------- fused aggregate + GEMM (dual-node + prefetched-index gather) ----------------
// C = (t(X_self) + sum_nb t(X_nb)) @ W^T + bias ; t = TR ? relu(bn(x)) : x
// Phase1: 16 groups x 16 lanes; each group processes rows (r, r+16) together:
// 2 coalesced csr index loads -> width-16 shfl broadcast -> 8 row loads in flight.
template <int TR>
__global__ __launch_bounds__(256, 4)
void k_ag(const u16* __restrict__ X, const int* __restrict__ rp,
          const int* __restrict__ csr, const u16* __restrict__ W,
          const float* __restrict__ bias,
          const float* __restrict__ statsIn, const float* __restrict__ gIn,
          const float* __restrict__ beIn, float invN,
          u16* __restrict__ Cc, float* __restrict__ statsOut, int do_stats, int N) {
  __shared__ u16 ls[128 * 128];     // 32KB: A-tile, then W, then C restage
  __shared__ float swave[4][256];
  __shared__ float bnTot[256];

  const int t = threadIdx.x;
  const int wv = t >> 6, lane = t & 63;
  const int rowBase = blockIdx.x * 128;
  const int gid = t >> 4;           // group 0..15
  const int li = t & 15;            // lane in group
  const int cb = li * 8;            // 8 bf16 columns per lane

  float s[8], h[8];
  if constexpr (TR) {
    float tv = 0.f;
#pragma unroll 8
    for (int sidx = 0; sidx < NSLOT; ++sidx) tv += statsIn[sidx * 256 + t];
    bnTot[t] = tv;
    __syncthreads();
#pragma unroll
    for (int j = 0; j < 8; ++j) {
      int c = cb + j;
      float mean = bnTot[c] * invN;
      float var = bnTot[128 + c] * invN - mean * mean;
      float rs = rsqrtf(var + BN_EPS);
      s[j] = gIn[c] * rs;
      h[j] = beIn[c] - mean * s[j];
    }
  }

  auto accum = [&](float* acc, uint4 v) {
    u32 w[4] = {v.x, v.y, v.z, v.w};
#pragma unroll
    for (int q = 0; q < 4; ++q) {
      float f0 = bf2f(w[q] & 0xFFFFu);
      float f1 = bf2f(w[q] >> 16);
      if constexpr (TR) {
        f0 = fmaxf(f0 * s[2 * q] + h[2 * q], 0.f);
        f1 = fmaxf(f1 * s[2 * q + 1] + h[2 * q + 1], 0.f);
      }
      acc[2 * q] += f0;
      acc[2 * q + 1] += f1;
    }
  };
  auto rowp = [&](int idx) {
    return (const uint4*)(X + (size_t)idx * D + cb);
  };
  // rare path: finish one node's adjacency beyond its first 16 entries
  auto slowTail = [&](float* acc, int b, int deg) {
#pragma unroll 1
    for (int base = 16; base < deg; base += 16) {
      int nrem = deg - base;
      if (nrem > 16) nrem = 16;
      int idx = (li < nrem) ? csr[b + base + li] : 0;
      int k = 0;
#pragma unroll 1
      for (; k + 3 < nrem; k += 4) {
        int s0 = __shfl(idx, k, 16);
        int s1 = __shfl(idx, k + 1, 16);
        int s2 = __shfl(idx, k + 2, 16);
        int s3 = __shfl(idx, k + 3, 16);
        uint4 v0 = *rowp(s0);
        uint4 v1 = *rowp(s1);
        uint4 v2 = *rowp(s2);
        uint4 v3 = *rowp(s3);
        accum(acc, v0); accum(acc, v1); accum(acc, v2); accum(acc, v3);
      }
      for (; k < nrem; ++k) {
        int s0 = __shfl(idx, k, 16);
        accum(acc, *rowp(s0));
      }
    }
  };

  // ---- phase 1: dual-node gather with coalesced index prefetch ----
#pragma unroll 1
  for (int jj = 0; jj < 4; ++jj) {
    const int r0 = gid + 32 * jj;   // rows r0 and r0+16
    const int r1 = r0 + 16;
    const int node0 = rowBase + r0, node1 = rowBase + r1;
    float a0[8], a1[8];
#pragma unroll
    for (int q = 0; q < 8; ++q) { a0[q] = 0.f; a1[q] = 0.f; }

    const bool in0 = node0 < N, in1 = node1 < N;
    int b0 = 0, d0 = 0, b1 = 0, d1 = 0;
    if (in0) { b0 = rp[node0]; d0 = rp[node0 + 1] - b0; }
    if (in1) { b1 = rp[node1]; d1 = rp[node1 + 1] - b1; }
    if (in0) accum(a0, *rowp(node0));   // self rows (2 loads in flight)
    if (in1) accum(a1, *rowp(node1));

    // first batch of each node (covers deg<=16, i.e. ~99.98% of nodes)
    int n0 = d0 > 16 ? 16 : d0;
    int n1 = d1 > 16 ? 16 : d1;
    int idx0 = (li < n0) ? csr[b0 + li] : 0;   // two coalesced index loads
    int idx1 = (li < n1) ? csr[b1 + li] : 0;
    int k0 = 0, k1 = 0;
    // dual main loop: 8 independent row loads in flight
    while (k0 + 3 < n0 && k1 + 3 < n1) {
      int s00 = __shfl(idx0, k0, 16), s01 = __shfl(idx0, k0 + 1, 16);
      int s02 = __shfl(idx0, k0 + 2, 16), s03 = __shfl(idx0, k0 + 3, 16);
      int s10 = __shfl(idx1, k1, 16), s11 = __shfl(idx1, k1 + 1, 16);
      int s12 = __shfl(idx1, k1 + 2, 16), s13 = __shfl(idx1, k1 + 3, 16);
      uint4 v00 = *rowp(s00);
      uint4 v01 = *rowp(s01);
      uint4 v02 = *rowp(s02);
      uint4 v03 = *rowp(s03);
      uint4 v10 = *rowp(s10);
      uint4 v11 = *rowp(s11);
      uint4 v12 = *rowp(s12);
      uint4 v13 = *rowp(s13);
      accum(a0, v00); accum(a0, v01); accum(a0, v02); accum(a0, v03);
      accum(a1, v10); accum(a1, v11); accum(a1, v12); accum(a1, v13);
      k0 += 4; k1 += 4;
    }
    // node0 remainder of first batch
    for (; k0 + 3 < n0; k0 += 4) {
      int s00 = __shfl(idx0, k0, 16), s01 = __shfl(idx0, k0 + 1, 16);
      int s02 = __shfl(idx0, k0 + 2, 16), s03 = __shfl(idx0, k0 + 3, 16);
      uint4 v00 = *rowp(s00);
      uint4 v01 = *rowp(s01);
      uint4 v02 = *rowp(s02);
      uint4 v03 = *rowp(s03);
      accum(a0, v00); accum(a0, v01); accum(a0, v02); accum(a0, v03);
    }
    for (; k0 < n0; ++k0) {
      int s0 = __shfl(idx0, k0, 16);
      accum(a0, *rowp(s0));
    }
    // node1 remainder of first batch
    for (; k1 + 3 < n1; k1 += 4) {
      int s10 = __shfl(idx1, k1, 16), s11 = __shfl(idx1, k1 + 1, 16);
      int s12 = __shfl(idx1, k1 + 2, 16), s13 = __shfl(idx1, k1 + 3, 16);
      uint4 v10 = *rowp(s10);
      uint4 v11 = *rowp(s11);
      uint4 v12 = *rowp(s12);
      uint4 v13 = *rowp(s13);
      accum(a1, v10); accum(a1, v11); accum(a1, v12); accum(a1, v13);
    }
    for (; k1 < n1; ++k1) {
      int s1 = __shfl(idx1, k1, 16);
      accum(a1, *rowp(s1));
    }
    // rare overflow batches (deg > 16)
    if (d0 > 16) slowTail(a0, b0, d0);
    if (d1 > 16) slowTail(a1, b1, d1);

    uint4 p0 = make_uint4(pack2(a0[0], a0[1]), pack2(a0[2], a0[3]),
                          pack2(a0[4], a0[5]), pack2(a0[6], a0[7]));
    uint4 p1 = make_uint4(pack2(a1[0], a1[1]), pack2(a1[2], a1[3]),
                          pack2(a1[4], a1[5]), pack2(a1[6], a1[7]));
    *(uint4*)((char*)ls + CSWZ(r0, r0 * 256 + li * 16)) = p0;
    *(uint4*)((char*)ls + CSWZ(r1, r1 * 256 + li * 16)) = p1;
  }
  __syncthreads();

  // ---- phase 2: A-frags LDS -> regs ----
  const int lrow = lane & 15;
  const int sb16 = (lane >> 4) << 4;
  short8 af[2][4];
#pragma unroll
  for (int m = 0; m < 2; ++m) {
    int r2 = wv * 32 + m * 16 + lrow;
#pragma unroll
    for (int s4 = 0; s4 < 4; ++s4)
      af[m][s4] = *(const short8*)((const char*)ls + CSWZ(r2, r2 * 256 + s4 * 64 + sb16));
  }
  __syncthreads();  // all A reads done before ls is overwritten with W

  // ---- phase 3: stage W (source pre-swizzled so linear LDS == CSWZ layout) ----
#pragma unroll
  for (int i = 0; i < 8; ++i) {
    int d = (i * 256 + t) * 16;
    gload16((const char*)W + CSWZ(d >> 8, d), (char*)ls + (i * 4096 + wv * 1024));
  }

  f32x4 acc2[2][8];
#pragma unroll
  for (int m = 0; m < 2; ++m)
#pragma unroll
    for (int n = 0; n < 8; ++n)
      acc2[m][n] = (f32x4){0.f, 0.f, 0.f, 0.f};

  __syncthreads();  // W staged (barrier drains gload16 vmcnt)

  // ---- phase 4: MFMA ----
#pragma unroll
  for (int s4 = 0; s4 < 4; ++s4) {
    const int cbb = s4 * 64 + sb16;
#pragma unroll
    for (int n = 0; n < 8; ++n) {
      int rw = n * 16 + lrow;
      short8 bw = *(const short8*)((const char*)ls + CSWZ(rw, rw * 256 + cbb));
#pragma unroll
      for (int m = 0; m < 2; ++m)
        acc2[m][n] = __builtin_amdgcn_mfma_f32_16x16x32_bf16(af[m][s4], bw, acc2[m][n], 0, 0, 0);
    }
  }

  // ---- epilogue ----
  __syncthreads();  // all W reads done before overwrite

  const int rgrp = (lane >> 4) << 2;
  float sacc[8], qacc[8];
#pragma unroll
  for (int n = 0; n < 8; ++n) { sacc[n] = 0.f; qacc[n] = 0.f; }

#pragma unroll
  for (int m = 0; m < 2; ++m) {
    int rl = wv * 32 + m * 16 + rgrp;
#pragma unroll
    for (int n = 0; n < 8; ++n) {
      int col = n * 16 + lrow;
      float bb = bias[col];
      f32x4 a = acc2[m][n];
#pragma unroll
      for (int r = 0; r < 4; ++r) {
        int row = rl + r;
        float vv = a[r] + bb;
        *(u16*)((char*)ls + CSWZ(row, row * 256 + col * 2)) = f2bf(vv);
        if (rowBase + row < N) { sacc[n] += vv; qacc[n] += vv * vv; }
      }
    }
  }
  if (do_stats) {
#pragma unroll
    for (int n = 0; n < 8; ++n) {
      float ss = sacc[n], q = qacc[n];
      ss += __shfl_xor(ss, 16, 64); q += __shfl_xor(q, 16, 64);
      ss += __shfl_xor(ss, 32, 64); q += __shfl_xor(q, 32, 64);
      if (lane < 16) {
        int col = n * 16 + lrow;
        swave[wv][col] = ss;
        swave[wv][128 + col] = q;
      }
    }
  }
  __syncthreads();

#pragma unroll
  for (int i = 0; i < 8; ++i) {
    int chunk = i * 256 + t;
    u32 so = (u32)chunk << 4;
    int row = so >> 8;
    if (rowBase + row < N) {
      uint4 v = *(const uint4*)((const char*)ls + CSWZ(row, so));
      *(uint4*)((char*)Cc + (size_t)(rowBase + row) * 256 + (so & 255)) = v;
    }
  }
  if (do_stats) {
    float tot = swave[0][t] + swave[1][t] + swave[2][t] + swave[3][t];
    atomicAdd(&statsOut[(blockIdx.x & (NSLOT - 1)) * 256 + t], tot);
  }
}

// ---------------- fused GEMM (dense A): C = t(A) @ W^T + bias ----------------
// MODE 0: A bf16, global_load_lds direct (pre-swizzled source)
// MODE 1: A bf16, relu(bn(A)) on load; BN from slotted statsIn (in-block reduce).
template <int MODE>
__global__ __launch_bounds__(256, 4)
void k_gemm2(const u16* __restrict__ A, const u16* __restrict__ W,
             const float* __restrict__ bias,
             const float* __restrict__ statsIn, const float* __restrict__ gIn,
             const float* __restrict__ beIn, float invN,
             u16* __restrict__ Cc, float* __restrict__ statsOut, int do_stats, int N) {
  __shared__ u16 ls[128 * 128];
  __shared__ float swave[4][256];
  __shared__ float bnTot[256];
  u16* lsA = ls;
  u16* lsW = ls + 64 * 128;

  const int t = threadIdx.x;
  const int wv = t >> 6;
  const int lane = t & 63;
  const int rowBase = blockIdx.x * 128;
  const int lrow = lane & 15;
  const int lkb = (lane >> 4) << 4;
  const int ch = lane & 7;

  if constexpr (MODE == 1) {
    float tv = 0.f;
#pragma unroll 8
    for (int sidx = 0; sidx < NSLOT; ++sidx) tv += statsIn[sidx * 256 + t];
    bnTot[t] = tv;
    __syncthreads();
  }

  f32x4 acc[2][8];
#pragma unroll
  for (int m = 0; m < 2; ++m)
#pragma unroll
    for (int n = 0; n < 8; ++n)
      acc[m][n] = (f32x4){0.f, 0.f, 0.f, 0.f};

#pragma unroll
  for (int hh = 0; hh < 2; ++hh) {
    if (hh) __syncthreads();

    float scx[8], shx[8];
    if constexpr (MODE == 1) {
#pragma unroll
      for (int j = 0; j < 8; ++j) {
        int c = hh * 64 + ch * 8 + j;
        float mean = bnTot[c] * invN;
        float var = bnTot[128 + c] * invN - mean * mean;
        float rs = rsqrtf(var + BN_EPS);
        scx[j] = gIn[c] * rs;
        shx[j] = beIn[c] - mean * scx[j];
      }
    }

#pragma unroll
    for (int i = 0; i < 4; ++i) {
      int r0 = wv * 32 + i * 8;
      int r = r0 + (lane >> 3);
      int sxcol = (ch << 4) ^ ((r & 7) << 4);
      gload16((const char*)W + (size_t)r * 256 + hh * 128 + sxcol,
              (char*)lsW + r0 * 128);
      if constexpr (MODE == 0) {
        int gr = rowBase + r;
        if (gr >= N) gr = N - 1;  // clamp (dup row; stores/stats guarded later)
        gload16((const char*)A + (size_t)gr * 256 + hh * 128 + sxcol,
                (char*)lsA + r0 * 128);
      } else {
        int gr = rowBase + r;
        uint4 v = make_uint4(0, 0, 0, 0);
        if (gr < N) v = *(const uint4*)(A + (size_t)gr * D + hh * 64 + ch * 8);
        u32 vv[4] = {v.x, v.y, v.z, v.w};
#pragma unroll
        for (int j = 0; j < 4; ++j) {
          float f0 = fmaxf(bf2f(vv[j] & 0xFFFFu) * scx[2 * j] + shx[2 * j], 0.f);
          float f1 = fmaxf(bf2f(vv[j] >> 16) * scx[2 * j + 1] + shx[2 * j + 1], 0.f);
          vv[j] = pack2(f0, f1);
        }
        u32 sz = (u32)ASWZ(r, r * 128 + ch * 16);
        *(uint4*)((char*)lsA + sz) = make_uint4(vv[0], vv[1], vv[2], vv[3]);
      }
    }
    __syncthreads();

#pragma unroll
    for (int kk2 = 0; kk2 < 2; ++kk2) {
      const int cb = kk2 * 64 + lkb;
      short8 af[2];
#pragma unroll
      for (int m = 0; m < 2; ++m) {
        int r = wv * 32 + m * 16 + lrow;
        af[m] = *(const short8*)((const char*)lsA + ASWZ(r, r * 128 + cb));
      }
#pragma unroll
      for (int n = 0; n < 8; ++n) {
        int rw = n * 16 + lrow;
        short8 bw = *(const short8*)((const char*)lsW + ASWZ(rw, rw * 128 + cb));
#pragma unroll
        for (int m = 0; m < 2; ++m)
          acc[m][n] = __builtin_amdgcn_mfma_f32_16x16x32_bf16(af[m], bw, acc[m][n], 0, 0, 0);
      }
    }
  }

  __syncthreads();

  const int rgrp = (lane >> 4) << 2;
  float sacc[8], qacc[8];
#pragma unroll
  for (int n = 0; n < 8; ++n) { sacc[n] = 0.f; qacc[n] = 0.f; }

#pragma unroll
  for (int m = 0; m < 2; ++m) {
    int rl = wv * 32 + m * 16 + rgrp;
#pragma unroll
    for (int n = 0; n < 8; ++n) {
      int col = n * 16 + lrow;
      float bb = bias[col];
      f32x4 a = acc[m][n];
#pragma unroll
      for (int r = 0; r < 4; ++r) {
        int row = rl + r;
        float vv = a[r] + bb;
        *(u16*)((char*)ls + CSWZ(row, row * 256 + col * 2)) = f2bf(vv);
        if (rowBase + row < N) { sacc[n] += vv; qacc[n] += vv * vv; }
      }
    }
  }
  if (do_stats) {
#pragma unroll
    for (int n = 0; n < 8; ++n) {
      float ss = sacc[n], q = qacc[n];
      ss += __shfl_xor(ss, 16, 64); q += __shfl_xor(q, 16, 64);
      ss += __shfl_xor(ss, 32, 64); q += __shfl_xor(q, 32, 64);
      if (lane < 16) {
        int col = n * 16 + lrow;
        swave[wv][col] = ss;
        swave[wv][128 + col] = q;
      }
    }
  }
  __syncthreads();

#pragma unroll
  for (int i = 0; i < 8; ++i) {
    int chunk = i * 256 + t;
    u32 so = (u32)chunk << 4;
    int row = so >> 8;
    if (rowBase + row < N) {
      uint4 v = *(const uint4*)((const char*)ls + CSWZ(row, so));
      *(uint4*)((char*)Cc + (size_t)(rowBase + row) * 256 + (so & 255)) = v;
    }
  }
  if (do_stats) {
    float tot = swave[0][t] + swave[1][t] + swave[2][t] + swave[3][t];
    atomicAdd(&statsOut[(blockIdx.x & (NSLOT - 1)) * 256 + t], tot);
  }
}

// ---------------- final stats reduce: slotted stats -> scale/shift ----------------
__global__ __launch_bounds__(256)
void k_fin(const float* __restrict__ stats, const float* __restrict__ g,
           const float* __restrict__ be, float* __restrict__ scale,
           float* __restrict__ shift, float invN) {
  __shared__ float totsh[256];
  int t = threadIdx.x;
  float tv = 0.f;
#pragma unroll 8
  for (int sidx = 0; sidx < NSLOT; ++sidx) tv += stats[sidx * 256 + t];
  totsh[t] = tv;
  __syncthreads();
  if (t < 128) {
    float mean = totsh[t] * invN;
    float var = totsh[128 + t] * invN - mean * mean;
    float rs = rsqrtf(var + BN_EPS);
    float sc = g[t] * rs;
    scale[t] = sc;
    shift[t] = be[t] - mean * sc;
  }
}

// ---------------- final: out = relu(bn(X))[mask] @ W_out^T + b_out ----------------
#define COUT 10
__global__ __launch_bounds__(256)
void k_out(const u16* __restrict__ X, const int* __restrict__ mask,
           const float* __restrict__ scale, const float* __restrict__ shift,
           const float* __restrict__ Wout, const float* __restrict__ bout,
           float* __restrict__ out, int M) {
  int w = blockIdx.x * 4 + (threadIdx.x >> 6);
  if (w >= M) return;
  int lane = threadIdx.x & 63;
  int c0 = lane * 2;
  int node = mask[w];
  u32 v = *(const u32*)(X + (size_t)node * D + c0);
  float a0 = fmaxf(bf2f(v & 0xFFFFu) * scale[c0] + shift[c0], 0.f);
  float a1 = fmaxf(bf2f(v >> 16) * scale[c0 + 1] + shift[c0 + 1], 0.f);
  float p[COUT];
#pragma unroll
  for (int c = 0; c < COUT; ++c) {
    float2 wv = *(const float2*)(Wout + c * D + c0);
    p[c] = a0 * wv.x + a1 * wv.y;
  }
#pragma unroll
  for (int c = 0; c < COUT; ++c) {
#pragma unroll
    for (int o = 32; o >= 1; o >>= 1)
      p[c] += __shfl_xor(p[c], o, 64);
  }
  if (lane == 0) {
#pragma unroll
    for (int c = 0; c < COUT; ++c)
      out[(size_t)w * COUT + c] = p[c] + bout[c];
  }
}

// ---------------- host ----------------
extern "C" void kernel_launch(void* const* d_in, const int* in_sizes, int n_in,
                              void* d_out, int out_size, void* d_ws, size_t ws_size,
                              hipStream_t stream) {
  const float* x      = (const float*)d_in[0];
  const int*   ei     = (const int*)d_in[1];
  const int*   mask   = (const int*)d_in[2];
  const float* W_init = (const float*)d_in[3];
  const float* b_init = (const float*)d_in[4];
  const float* W1s    = (const float*)d_in[5];
  const float* b1s    = (const float*)d_in[6];
  const float* g1s    = (const float*)d_in[7];
  const float* be1s   = (const float*)d_in[8];
  const float* W2s    = (const float*)d_in[9];
  const float* b2s    = (const float*)d_in[10];
  const float* g2s    = (const float*)d_in[11];
  const float* be2s   = (const float*)d_in[12];
  const float* W_out  = (const float*)d_in[13];
  const float* b_out  = (const float*)d_in[14];

  const int N = in_sizes[0] / D;
  const int E = in_sizes[1] / 2;
  const int M = in_sizes[2];
  const int L = in_sizes[6] / D;

  const int* srcp = ei;
  const int* dstp = ei + E;

  char* ws = (char*)d_ws;
  size_t off = 0;
  auto take = [&](size_t bytes) -> char* {
    off = (off + 255) & ~(size_t)255;
    char* p = ws + off;
    off += bytes;
    return p;
  };
  const int GB = (N + 127) / 128;
  const size_t SBUF = (size_t)NSLOT * 256;           // floats per stats buffer
  u16* B0    = (u16*)take((size_t)N * D * 2);
  u16* B1    = (u16*)take((size_t)N * D * 2);
  u16* Wb    = (u16*)take((size_t)(1 + 2 * L) * D * D * 2);
  int* csr   = (int*)take((size_t)E * 4);
  int* rp    = (int*)take((size_t)(N + 1) * 4);
  int* cnt   = (int*)take((size_t)N * 8 + 8 * SBUF * 4);  // cnt | fill | 8 slotted stats bufs
  int* fill  = cnt + N;
  float* stats = (float*)(cnt + 2 * N);
  int* bsum  = (int*)take(4096);
  float* scaleF = (float*)take(512);
  float* shiftF = (float*)take(512);
  if (off > ws_size) return;

  hipMemsetAsync(cnt, 0, (size_t)N * 8 + 8 * SBUF * 4, stream);

  // front: convert x + convert weights + edge count (one dispatch)
  {
    int n4x = N * D / 4;
    int nbx = (n4x + 255) / 256;
    int na = D * D / 4;
    int nb = L * D * D / 4;
    int nbw = (na + 2 * nb + 255) / 256;
    int nbe = (E + 255) / 256;
    k_front<<<nbx + nbw + nbe, 256, 0, stream>>>(
        x, B0, n4x, nbx,
        W_init, W1s, W2s, Wb, Wb + (size_t)D * D, Wb + (size_t)(1 + L) * D * D,
        na, nb, nbw, dstp, cnt, E);
  }

  // CSR build
  int NB = (N + 255) / 256;
  k_scan1<<<NB, 256, 0, stream>>>(cnt, rp, bsum, N);
  k_scan2<<<1, 512, 0, stream>>>(bsum, NB);
  k_scan3<<<NB, 256, 0, stream>>>(rp, bsum, N, E);
  k_scatter<<<(E + 255) / 256, 256, 0, stream>>>(srcp, dstp, rp, fill, csr, E);

  float invN = 1.0f / (float)N;

  // init linear: B1 = B0 @ W_init^T + b_init (bf16 A, gload_lds direct)
  k_gemm2<0><<<GB, 256, 0, stream>>>(B0, Wb, b_init,
                                     nullptr, nullptr, nullptr, invN,
                                     B1, stats, 0, N);

  for (int l = 0; l < L; ++l) {
    float* sAG = stats + (size_t)(2 * l) * SBUF;       // k_ag output stats
    float* sG2 = stats + (size_t)(2 * l + 1) * SBUF;   // gemm2<1> output stats
    // B0 = agg(t(B1)) @ W1^T + b1 ; t uses prev layer's second BN
    if (l == 0)
      k_ag<0><<<GB, 256, 0, stream>>>(B1, rp, csr, Wb + (size_t)(1 + l) * D * D,
                                      b1s + l * D, nullptr, nullptr, nullptr, invN,
                                      B0, sAG, 1, N);
    else
      k_ag<1><<<GB, 256, 0, stream>>>(B1, rp, csr, Wb + (size_t)(1 + l) * D * D,
                                      b1s + l * D, stats + (size_t)(2 * l - 1) * SBUF,
                                      g2s + (l - 1) * D, be2s + (l - 1) * D, invN,
                                      B0, sAG, 1, N);
    // B1 = relu(bn1(B0)) @ W2^T + b2
    k_gemm2<1><<<GB, 256, 0, stream>>>(B0, Wb + (size_t)(1 + L + l) * D * D, b2s + l * D,
                                       sAG, g1s + l * D, be1s + l * D, invN,
                                       B1, sG2, 1, N);
  }

  // final BN params + masked output
  k_fin<<<1, 256, 0, stream>>>(stats + (size_t)(2 * L - 1) * SBUF,
                               g2s + (L - 1) * D, be2s + (L - 1) * D,
                               scaleF, shiftF, invN);
  k_out<<<(M + 3) / 4, 256, 0, stream>>>(B1, mask, scaleF, shiftF,
                                         W_out, b_out, (float*)d_out, M);
}

// Round 18
// 377.947 us; speedup vs baseline: 1.1796x; 1.1796x over previous
//
#include <hip/hip_runtime.h>
#include <hip/hip_bf16.h>
#include <stdint.h>

#define D 128
#define NSLOT 32

typedef unsigned int u32;
typedef unsigned short u16;
typedef __attribute__((ext_vector_type(8))) short short8;
typedef __attribute__((ext_vector_type(4))) float f32x4;

__device__ __forceinline__ float bf2f(u32 lo16) {
  return __uint_as_float(lo16 << 16);
}
__device__ __forceinline__ u16 f2bf(float f) {
  u32 u = __float_as_uint(f);
  u32 r = (u + 0x7FFFu + ((u >> 16) & 1u)) >> 16;
  return (u16)r;
}
__device__ __forceinline__ u32 pack2(float a, float b) {
  return (u32)f2bf(a) | ((u32)f2bf(b) << 16);
}

// async global->LDS, 16B per lane; lds dest must be wave-uniform base (+lane*16)
__device__ __forceinline__ void gload16(const void* g, void* l) {
  __builtin_amdgcn_global_load_lds(
      (const __attribute__((address_space(1))) u32*)g,
      (__attribute__((address_space(3))) u32*)l, 16, 0, 0);
}

// swizzles (involutions on byte offsets)
#define ASWZ(r, b) ((b) ^ (((r)&7) << 4))                      // 128B rows
#define CSWZ(r, b) ((b) ^ (((r)&7) << 4) ^ (((r)&8) << 1))     // 256B rows

#define BN_EPS 1e-5f

// ---------------- merged front: convert x, convert weights, edge count ----------------
__global__ __launch_bounds__(256)
void k_front(const float* __restrict__ x, u16* __restrict__ B0, int n4x, int nbx,
             const float* __restrict__ Wi, const float* __restrict__ W1,
             const float* __restrict__ W2, u16* __restrict__ oWi,
             u16* __restrict__ oW1, u16* __restrict__ oW2, int na, int nb, int nbw,
             const int* __restrict__ dst, int* __restrict__ cnt, int E) {
  int b = blockIdx.x;
  if (b < nbx) {
    int i = b * 256 + threadIdx.x;
    if (i < n4x) {
      float4 v = ((const float4*)x)[i];
      ushort4 o;
      o.x = f2bf(v.x); o.y = f2bf(v.y); o.z = f2bf(v.z); o.w = f2bf(v.w);
      ((ushort4*)B0)[i] = o;
    }
  } else if (b < nbx + nbw) {
    int i = (b - nbx) * 256 + threadIdx.x;
    const float* in;
    u16* out;
    int idx;
    if (i < na) { in = Wi; out = oWi; idx = i; }
    else if (i < na + nb) { in = W1; out = oW1; idx = i - na; }
    else if (i < na + 2 * nb) { in = W2; out = oW2; idx = i - na - nb; }
    else return;
    float4 v = ((const float4*)in)[idx];
    ushort4 o;
    o.x = f2bf(v.x); o.y = f2bf(v.y); o.z = f2bf(v.z); o.w = f2bf(v.w);
    ((ushort4*)out)[idx] = o;
  } else {
    int e = (b - nbx - nbw) * 256 + threadIdx.x;
    if (e < E) atomicAdd(&cnt[dst[e]], 1);
  }
}

// ---------------- CSR build ----------------
__global__ void k_scan1(const int* __restrict__ cnt, int* __restrict__ rp,
                        int* __restrict__ bsum, int N) {
  __shared__ int sh[256];
  int tid = threadIdx.x;
  int i = blockIdx.x * 256 + tid;
  int v = (i < N) ? cnt[i] : 0;
  sh[tid] = v;
  __syncthreads();
  for (int o = 1; o < 256; o <<= 1) {
    int x = (tid >= o) ? sh[tid - o] : 0;
    __syncthreads();
    sh[tid] += x;
    __syncthreads();
  }
  if (i < N) rp[i] = sh[tid] - v;
  if (tid == 255) bsum[blockIdx.x] = sh[255];
}

__global__ void k_scan2(int* __restrict__ bsum, int NB) {
  __shared__ int sh[512];
  int tid = threadIdx.x;
  int v = (tid < NB) ? bsum[tid] : 0;
  sh[tid] = v;
  __syncthreads();
  for (int o = 1; o < 512; o <<= 1) {
    int x = (tid >= o) ? sh[tid - o] : 0;
    __syncthreads();
    sh[tid] += x;
    __syncthreads();
  }
  if (tid < NB) bsum[tid] = sh[tid] - v;
}

__global__ void k_scan3(int* __restrict__ rp, const int* __restrict__ bsum, int N, int E) {
  int i = blockIdx.x * 256 + threadIdx.x;
  if (i < N) rp[i] += bsum[blockIdx.x];
  if (i == 0) rp[N] = E;
}

__global__ void k_scatter(const int* __restrict__ src, const int* __restrict__ dst,
                          const int* __restrict__ rp, int* __restrict__ fill,
                          int* __restrict__ csr, int E) {
  int e = blockIdx.x * blockDim.x + threadIdx.x;
  if (e < E) {
    int d2 = dst[e];
    int pos = rp[d2] + atomicAdd(&fill[d2], 1);
    csr[pos] = src[e];
  }
}

// ---------------- fused aggregate + GEMM (prefetched-index gather, slotted BN stats) ----------------
// C = (t(X_self) + sum_nb t(X_nb)) @ W^T + bias ; t = TR ? relu(bn(x)) : x
// Phase1: 16 groups x 16 lanes; group loads 16 csr indices coalesced (1 load),
// broadcasts via width-16 shfl, issues 4 independent row loads per step.
template <int TR>
__global__ __launch_bounds__(256, 4)
void k_ag(const u16* __restrict__ X, const int* __restrict__ rp,
          const int* __restrict__ csr, const u16* __restrict__ W,
          const float* __restrict__ bias,
          const float* __restrict__ statsIn, const float* __restrict__ gIn,
          const float* __restrict__ beIn, float invN,
          u16* __restrict__ Cc, float* __restrict__ statsOut, int do_stats, int N) {
  __shared__ u16 ls[128 * 128];     // 32KB: A-tile, then W, then C restage
  __shared__ float swave[4][256];
  __shared__ float bnTot[256];

  const int t = threadIdx.x;
  const int wv = t >> 6, lane = t & 63;
  const int rowBase = blockIdx.x * 128;
  const int gid = t >> 4;           // group 0..15
  const int li = t & 15;            // lane in group
  const int cb = li * 8;            // 8 bf16 columns per lane

  float s[8], h[8];
  if constexpr (TR) {
    float tv = 0.f;
#pragma unroll 8
    for (int sidx = 0; sidx < NSLOT; ++sidx) tv += statsIn[sidx * 256 + t];
    bnTot[t] = tv;
    __syncthreads();
#pragma unroll
    for (int j = 0; j < 8; ++j) {
      int c = cb + j;
      float mean = bnTot[c] * invN;
      float var = bnTot[128 + c] * invN - mean * mean;
      float rs = rsqrtf(var + BN_EPS);
      s[j] = gIn[c] * rs;
      h[j] = beIn[c] - mean * s[j];
    }
  }

  auto accum = [&](float* acc, uint4 v) {
    u32 w[4] = {v.x, v.y, v.z, v.w};
#pragma unroll
    for (int q = 0; q < 4; ++q) {
      float f0 = bf2f(w[q] & 0xFFFFu);
      float f1 = bf2f(w[q] >> 16);
      if constexpr (TR) {
        f0 = fmaxf(f0 * s[2 * q] + h[2 * q], 0.f);
        f1 = fmaxf(f1 * s[2 * q + 1] + h[2 * q + 1], 0.f);
      }
      acc[2 * q] += f0;
      acc[2 * q + 1] += f1;
    }
  };
  auto rowp = [&](int idx) {
    return (const uint4*)(X + (size_t)idx * D + cb);
  };

  // ---- phase 1: gather-aggregate with coalesced index prefetch ----
#pragma unroll 1
  for (int j = 0; j < 8; ++j) {
    const int r = gid + 16 * j;     // local row 0..127
    const int node = rowBase + r;
    float acc[8];
#pragma unroll
    for (int q = 0; q < 8; ++q) acc[q] = 0.f;

    if (node < N) {
      uint4 vs = *rowp(node);       // self row (issued first, independent)
      int b = rp[node];
      int deg = rp[node + 1] - b;
      accum(acc, vs);
#pragma unroll 1
      for (int base = 0; base < deg; base += 16) {
        int nrem = deg - base;
        if (nrem > 16) nrem = 16;
        int idx = (li < nrem) ? csr[b + base + li] : 0;  // one coalesced load
        int k = 0;
#pragma unroll 1
        for (; k + 3 < nrem; k += 4) {
          int s0 = __shfl(idx, k, 16);
          int s1 = __shfl(idx, k + 1, 16);
          int s2 = __shfl(idx, k + 2, 16);
          int s3 = __shfl(idx, k + 3, 16);
          uint4 v0 = *rowp(s0);
          uint4 v1 = *rowp(s1);
          uint4 v2 = *rowp(s2);
          uint4 v3 = *rowp(s3);
          accum(acc, v0); accum(acc, v1); accum(acc, v2); accum(acc, v3);
        }
        if (k < nrem) {
          const bool h1 = (k + 1 < nrem), h2 = (k + 2 < nrem);
          int s0 = __shfl(idx, k, 16);
          int s1 = __shfl(idx, h1 ? k + 1 : k, 16);
          int s2 = __shfl(idx, h2 ? k + 2 : k, 16);
          uint4 v0 = *rowp(s0);
          uint4 v1, v2;
          if (h1) v1 = *rowp(s1);
          if (h2) v2 = *rowp(s2);
          accum(acc, v0);
          if (h1) accum(acc, v1);
          if (h2) accum(acc, v2);
        }
      }
    }
    uint4 pk = make_uint4(pack2(acc[0], acc[1]), pack2(acc[2], acc[3]),
                          pack2(acc[4], acc[5]), pack2(acc[6], acc[7]));
    *(uint4*)((char*)ls + CSWZ(r, r * 256 + li * 16)) = pk;
  }
  __syncthreads();

  // ---- phase 2: A-frags LDS -> regs ----
  const int lrow = lane & 15;
  const int sb16 = (lane >> 4) << 4;
  short8 af[2][4];
#pragma unroll
  for (int m = 0; m < 2; ++m) {
    int r2 = wv * 32 + m * 16 + lrow;
#pragma unroll
    for (int s4 = 0; s4 < 4; ++s4)
      af[m][s4] = *(const short8*)((const char*)ls + CSWZ(r2, r2 * 256 + s4 * 64 + sb16));
  }
  __syncthreads();  // all A reads done before ls is overwritten with W

  // ---- phase 3: stage W (source pre-swizzled so linear LDS == CSWZ layout) ----
#pragma unroll
  for (int i = 0; i < 8; ++i) {
    int d = (i * 256 + t) * 16;
    gload16((const char*)W + CSWZ(d >> 8, d), (char*)ls + (i * 4096 + wv * 1024));
  }

  f32x4 acc2[2][8];
#pragma unroll
  for (int m = 0; m < 2; ++m)
#pragma unroll
    for (int n = 0; n < 8; ++n)
      acc2[m][n] = (f32x4){0.f, 0.f, 0.f, 0.f};

  __syncthreads();  // W staged (barrier drains gload16 vmcnt)

  // ---- phase 4: MFMA ----
#pragma unroll
  for (int s4 = 0; s4 < 4; ++s4) {
    const int cbb = s4 * 64 + sb16;
#pragma unroll
    for (int n = 0; n < 8; ++n) {
      int rw = n * 16 + lrow;
      short8 bw = *(const short8*)((const char*)ls + CSWZ(rw, rw * 256 + cbb));
#pragma unroll
      for (int m = 0; m < 2; ++m)
        acc2[m][n] = __builtin_amdgcn_mfma_f32_16x16x32_bf16(af[m][s4], bw, acc2[m][n], 0, 0, 0);
    }
  }

  // ---- epilogue ----
  __syncthreads();  // all W reads done before overwrite

  const int rgrp = (lane >> 4) << 2;
  float sacc[8], qacc[8];
#pragma unroll
  for (int n = 0; n < 8; ++n) { sacc[n] = 0.f; qacc[n] = 0.f; }

#pragma unroll
  for (int m = 0; m < 2; ++m) {
    int rl = wv * 32 + m * 16 + rgrp;
#pragma unroll
    for (int n = 0; n < 8; ++n) {
      int col = n * 16 + lrow;
      float bb = bias[col];
      f32x4 a = acc2[m][n];
#pragma unroll
      for (int r = 0; r < 4; ++r) {
        int row = rl + r;
        float vv = a[r] + bb;
        *(u16*)((char*)ls + CSWZ(row, row * 256 + col * 2)) = f2bf(vv);
        if (rowBase + row < N) { sacc[n] += vv; qacc[n] += vv * vv; }
      }
    }
  }
  if (do_stats) {
#pragma unroll
    for (int n = 0; n < 8; ++n) {
      float ss = sacc[n], q = qacc[n];
      ss += __shfl_xor(ss, 16, 64); q += __shfl_xor(q, 16, 64);
      ss += __shfl_xor(ss, 32, 64); q += __shfl_xor(q, 32, 64);
      if (lane < 16) {
        int col = n * 16 + lrow;
        swave[wv][col] = ss;
        swave[wv][128 + col] = q;
      }
    }
  }
  __syncthreads();

#pragma unroll
  for (int i = 0; i < 8; ++i) {
    int chunk = i * 256 + t;
    u32 so = (u32)chunk << 4;
    int row = so >> 8;
    if (rowBase + row < N) {
      uint4 v = *(const uint4*)((const char*)ls + CSWZ(row, so));
      *(uint4*)((char*)Cc + (size_t)(rowBase + row) * 256 + (so & 255)) = v;
    }
  }
  if (do_stats) {
    float tot = swave[0][t] + swave[1][t] + swave[2][t] + swave[3][t];
    atomicAdd(&statsOut[(blockIdx.x & (NSLOT - 1)) * 256 + t], tot);
  }
}

// ---------------- fused GEMM (dense A): C = t(A) @ W^T + bias ----------------
// MODE 0: A bf16, global_load_lds direct (pre-swizzled source)
// MODE 1: A bf16, relu(bn(A)) on load; BN from slotted statsIn (in-block reduce).
template <int MODE>
__global__ __launch_bounds__(256, 4)
void k_gemm2(const u16* __restrict__ A, const u16* __restrict__ W,
             const float* __restrict__ bias,
             const float* __restrict__ statsIn, const float* __restrict__ gIn,
             const float* __restrict__ beIn, float invN,
             u16* __restrict__ Cc, float* __restrict__ statsOut, int do_stats, int N) {
  __shared__ u16 ls[128 * 128];
  __shared__ float swave[4][256];
  __shared__ float bnTot[256];
  u16* lsA = ls;
  u16* lsW = ls + 64 * 128;

  const int t = threadIdx.x;
  const int wv = t >> 6;
  const int lane = t & 63;
  const int rowBase = blockIdx.x * 128;
  const int lrow = lane & 15;
  const int lkb = (lane >> 4) << 4;
  const int ch = lane & 7;

  if constexpr (MODE == 1) {
    float tv = 0.f;
#pragma unroll 8
    for (int sidx = 0; sidx < NSLOT; ++sidx) tv += statsIn[sidx * 256 + t];
    bnTot[t] = tv;
    __syncthreads();
  }

  f32x4 acc[2][8];
#pragma unroll
  for (int m = 0; m < 2; ++m)
#pragma unroll
    for (int n = 0; n < 8; ++n)
      acc[m][n] = (f32x4){0.f, 0.f, 0.f, 0.f};

#pragma unroll
  for (int hh = 0; hh < 2; ++hh) {
    if (hh) __syncthreads();

    float scx[8], shx[8];
    if constexpr (MODE == 1) {
#pragma unroll
      for (int j = 0; j < 8; ++j) {
        int c = hh * 64 + ch * 8 + j;
        float mean = bnTot[c] * invN;
        float var = bnTot[128 + c] * invN - mean * mean;
        float rs = rsqrtf(var + BN_EPS);
        scx[j] = gIn[c] * rs;
        shx[j] = beIn[c] - mean * scx[j];
      }
    }

#pragma unroll
    for (int i = 0; i < 4; ++i) {
      int r0 = wv * 32 + i * 8;
      int r = r0 + (lane >> 3);
      int sxcol = (ch << 4) ^ ((r & 7) << 4);
      gload16((const char*)W + (size_t)r * 256 + hh * 128 + sxcol,
              (char*)lsW + r0 * 128);
      if constexpr (MODE == 0) {
        int gr = rowBase + r;
        if (gr >= N) gr = N - 1;  // clamp (dup row; stores/stats guarded later)
        gload16((const char*)A + (size_t)gr * 256 + hh * 128 + sxcol,
                (char*)lsA + r0 * 128);
      } else {
        int gr = rowBase + r;
        uint4 v = make_uint4(0, 0, 0, 0);
        if (gr < N) v = *(const uint4*)(A + (size_t)gr * D + hh * 64 + ch * 8);
        u32 vv[4] = {v.x, v.y, v.z, v.w};
#pragma unroll
        for (int j = 0; j < 4; ++j) {
          float f0 = fmaxf(bf2f(vv[j] & 0xFFFFu) * scx[2 * j] + shx[2 * j], 0.f);
          float f1 = fmaxf(bf2f(vv[j] >> 16) * scx[2 * j + 1] + shx[2 * j + 1], 0.f);
          vv[j] = pack2(f0, f1);
        }
        u32 sz = (u32)ASWZ(r, r * 128 + ch * 16);
        *(uint4*)((char*)lsA + sz) = make_uint4(vv[0], vv[1], vv[2], vv[3]);
      }
    }
    __syncthreads();

#pragma unroll
    for (int kk2 = 0; kk2 < 2; ++kk2) {
      const int cb = kk2 * 64 + lkb;
      short8 af[2];
#pragma unroll
      for (int m = 0; m < 2; ++m) {
        int r = wv * 32 + m * 16 + lrow;
        af[m] = *(const short8*)((const char*)lsA + ASWZ(r, r * 128 + cb));
      }
#pragma unroll
      for (int n = 0; n < 8; ++n) {
        int rw = n * 16 + lrow;
        short8 bw = *(const short8*)((const char*)lsW + ASWZ(rw, rw * 128 + cb));
#pragma unroll
        for (int m = 0; m < 2; ++m)
          acc[m][n] = __builtin_amdgcn_mfma_f32_16x16x32_bf16(af[m], bw, acc[m][n], 0, 0, 0);
      }
    }
  }

  __syncthreads();

  const int rgrp = (lane >> 4) << 2;
  float sacc[8], qacc[8];
#pragma unroll
  for (int n = 0; n < 8; ++n) { sacc[n] = 0.f; qacc[n] = 0.f; }

#pragma unroll
  for (int m = 0; m < 2; ++m) {
    int rl = wv * 32 + m * 16 + rgrp;
#pragma unroll
    for (int n = 0; n < 8; ++n) {
      int col = n * 16 + lrow;
      float bb = bias[col];
      f32x4 a = acc[m][n];
#pragma unroll
      for (int r = 0; r < 4; ++r) {
        int row = rl + r;
        float vv = a[r] + bb;
        *(u16*)((char*)ls + CSWZ(row, row * 256 + col * 2)) = f2bf(vv);
        if (rowBase + row < N) { sacc[n] += vv; qacc[n] += vv * vv; }
      }
    }
  }
  if (do_stats) {
#pragma unroll
    for (int n = 0; n < 8; ++n) {
      float ss = sacc[n], q = qacc[n];
      ss += __shfl_xor(ss, 16, 64); q += __shfl_xor(q, 16, 64);
      ss += __shfl_xor(ss, 32, 64); q += __shfl_xor(q, 32, 64);
      if (lane < 16) {
        int col = n * 16 + lrow;
        swave[wv][col] = ss;
        swave[wv][128 + col] = q;
      }
    }
  }
  __syncthreads();

#pragma unroll
  for (int i = 0; i < 8; ++i) {
    int chunk = i * 256 + t;
    u32 so = (u32)chunk << 4;
    int row = so >> 8;
    if (rowBase + row < N) {
      uint4 v = *(const uint4*)((const char*)ls + CSWZ(row, so));
      *(uint4*)((char*)Cc + (size_t)(rowBase + row) * 256 + (so & 255)) = v;
    }
  }
  if (do_stats) {
    float tot = swave[0][t] + swave[1][t] + swave[2][t] + swave[3][t];
    atomicAdd(&statsOut[(blockIdx.x & (NSLOT - 1)) * 256 + t], tot);
  }
}

// ---------------- final stats reduce: slotted stats -> scale/shift ----------------
__global__ __launch_bounds__(256)
void k_fin(const float* __restrict__ stats, const float* __restrict__ g,
           const float* __restrict__ be, float* __restrict__ scale,
           float* __restrict__ shift, float invN) {
  __shared__ float totsh[256];
  int t = threadIdx.x;
  float tv = 0.f;
#pragma unroll 8
  for (int sidx = 0; sidx < NSLOT; ++sidx) tv += stats[sidx * 256 + t];
  totsh[t] = tv;
  __syncthreads();
  if (t < 128) {
    float mean = totsh[t] * invN;
    float var = totsh[128 + t] * invN - mean * mean;
    float rs = rsqrtf(var + BN_EPS);
    float sc = g[t] * rs;
    scale[t] = sc;
    shift[t] = be[t] - mean * sc;
  }
}

// ---------------- final: out = relu(bn(X))[mask] @ W_out^T + b_out ----------------
#define COUT 10
__global__ __launch_bounds__(256)
void k_out(const u16* __restrict__ X, const int* __restrict__ mask,
           const float* __restrict__ scale, const float* __restrict__ shift,
           const float* __restrict__ Wout, const float* __restrict__ bout,
           float* __restrict__ out, int M) {
  int w = blockIdx.x * 4 + (threadIdx.x >> 6);
  if (w >= M) return;
  int lane = threadIdx.x & 63;
  int c0 = lane * 2;
  int node = mask[w];
  u32 v = *(const u32*)(X + (size_t)node * D + c0);
  float a0 = fmaxf(bf2f(v & 0xFFFFu) * scale[c0] + shift[c0], 0.f);
  float a1 = fmaxf(bf2f(v >> 16) * scale[c0 + 1] + shift[c0 + 1], 0.f);
  float p[COUT];
#pragma unroll
  for (int c = 0; c < COUT; ++c) {
    float2 wv = *(const float2*)(Wout + c * D + c0);
    p[c] = a0 * wv.x + a1 * wv.y;
  }
#pragma unroll
  for (int c = 0; c < COUT; ++c) {
#pragma unroll
    for (int o = 32; o >= 1; o >>= 1)
      p[c] += __shfl_xor(p[c], o, 64);
  }
  if (lane == 0) {
#pragma unroll
    for (int c = 0; c < COUT; ++c)
      out[(size_t)w * COUT + c] = p[c] + bout[c];
  }
}

// ---------------- host ----------------
extern "C" void kernel_launch(void* const* d_in, const int* in_sizes, int n_in,
                              void* d_out, int out_size, void* d_ws, size_t ws_size,
                              hipStream_t stream) {
  const float* x      = (const float*)d_in[0];
  const int*   ei     = (const int*)d_in[1];
  const int*   mask   = (const int*)d_in[2];
  const float* W_init = (const float*)d_in[3];
  const float* b_init = (const float*)d_in[4];
  const float* W1s    = (const float*)d_in[5];
  const float* b1s    = (const float*)d_in[6];
  const float* g1s    = (const float*)d_in[7];
  const float* be1s   = (const float*)d_in[8];
  const float* W2s    = (const float*)d_in[9];
  const float* b2s    = (const float*)d_in[10];
  const float* g2s    = (const float*)d_in[11];
  const float* be2s   = (const float*)d_in[12];
  const float* W_out  = (const float*)d_in[13];
  const float* b_out  = (const float*)d_in[14];

  const int N = in_sizes[0] / D;
  const int E = in_sizes[1] / 2;
  const int M = in_sizes[2];
  const int L = in_sizes[6] / D;

  const int* srcp = ei;
  const int* dstp = ei + E;

  char* ws = (char*)d_ws;
  size_t off = 0;
  auto take = [&](size_t bytes) -> char* {
    off = (off + 255) & ~(size_t)255;
    char* p = ws + off;
    off += bytes;
    return p;
  };
  const int GB = (N + 127) / 128;
  const size_t SBUF = (size_t)NSLOT * 256;           // floats per stats buffer
  u16* B0    = (u16*)take((size_t)N * D * 2);
  u16* B1    = (u16*)take((size_t)N * D * 2);
  u16* Wb    = (u16*)take((size_t)(1 + 2 * L) * D * D * 2);
  int* csr   = (int*)take((size_t)E * 4);
  int* rp    = (int*)take((size_t)(N + 1) * 4);
  int* cnt   = (int*)take((size_t)N * 8 + 8 * SBUF * 4);  // cnt | fill | 8 slotted stats bufs
  int* fill  = cnt + N;
  float* stats = (float*)(cnt + 2 * N);
  int* bsum  = (int*)take(4096);
  float* scaleF = (float*)take(512);
  float* shiftF = (float*)take(512);
  if (off > ws_size) return;

  hipMemsetAsync(cnt, 0, (size_t)N * 8 + 8 * SBUF * 4, stream);

  // front: convert x + convert weights + edge count (one dispatch)
  {
    int n4x = N * D / 4;
    int nbx = (n4x + 255) / 256;
    int na = D * D / 4;
    int nb = L * D * D / 4;
    int nbw = (na + 2 * nb + 255) / 256;
    int nbe = (E + 255) / 256;
    k_front<<<nbx + nbw + nbe, 256, 0, stream>>>(
        x, B0, n4x, nbx,
        W_init, W1s, W2s, Wb, Wb + (size_t)D * D, Wb + (size_t)(1 + L) * D * D,
        na, nb, nbw, dstp, cnt, E);
  }

  // CSR build
  int NB = (N + 255) / 256;
  k_scan1<<<NB, 256, 0, stream>>>(cnt, rp, bsum, N);
  k_scan2<<<1, 512, 0, stream>>>(bsum, NB);
  k_scan3<<<NB, 256, 0, stream>>>(rp, bsum, N, E);
  k_scatter<<<(E + 255) / 256, 256, 0, stream>>>(srcp, dstp, rp, fill, csr, E);

  float invN = 1.0f / (float)N;

  // init linear: B1 = B0 @ W_init^T + b_init (bf16 A, gload_lds direct)
  k_gemm2<0><<<GB, 256, 0, stream>>>(B0, Wb, b_init,
                                     nullptr, nullptr, nullptr, invN,
                                     B1, stats, 0, N);

  for (int l = 0; l < L; ++l) {
    float* sAG = stats + (size_t)(2 * l) * SBUF;       // k_ag output stats
    float* sG2 = stats + (size_t)(2 * l + 1) * SBUF;   // gemm2<1> output stats
    // B0 = agg(t(B1)) @ W1^T + b1 ; t uses prev layer's second BN
    if (l == 0)
      k_ag<0><<<GB, 256, 0, stream>>>(B1, rp, csr, Wb + (size_t)(1 + l) * D * D,
                                      b1s + l * D, nullptr, nullptr, nullptr, invN,
                                      B0, sAG, 1, N);
    else
      k_ag<1><<<GB, 256, 0, stream>>>(B1, rp, csr, Wb + (size_t)(1 + l) * D * D,
                                      b1s + l * D, stats + (size_t)(2 * l - 1) * SBUF,
                                      g2s + (l - 1) * D, be2s + (l - 1) * D, invN,
                                      B0, sAG, 1, N);
    // B1 = relu(bn1(B0)) @ W2^T + b2
    k_gemm2<1><<<GB, 256, 0, stream>>>(B0, Wb + (size_t)(1 + L + l) * D * D, b2s + l * D,
                                       sAG, g1s + l * D, be1s + l * D, invN,
                                       B1, sG2, 1, N);
  }

  // final BN params + masked output
  k_fin<<<1, 256, 0, stream>>>(stats + (size_t)(2 * L - 1) * SBUF,
                               g2s + (L - 1) * D, be2s + (L - 1) * D,
                               scaleF, shiftF, invN);
  k_out<<<(M + 3) / 4, 256, 0, stream>>>(B1, mask, scaleF, shiftF,
                                         W_out, b_out, (float*)d_out, M);
}